// Round 19
// baseline (150.135 us; speedup 1.0000x reference)
//
#include <hip/hip_runtime.h>

#define N_NODES   100000
#define N_EDGES   3200000
#define N_GRAPHS  1000
#define FEAT      512
#define EMB       7
#define HP        8      // padded per-node feature stride
#define N_CLASSES 10

#define BSH       7      // 128 nodes per bucket
#define DMASK     127
#define NBUCK     782    // ceil(100000/128)
#define TCOLS     783    // NBUCK+1 (row-end sentinel)
#define NB_A      512    // sort blocks
#define TILE_A    6250   // 512*6250 == 3.2M exactly
#define NIT       25     // ceil(TILE_A/256)
#define SEGCAP    4864   // bucket total: mean 4096, +12 sigma
#define GSPAN     16     // max graphs per bucket handled in LDS
#define MMF       391    // ALL matmul tiles in k_sortblk (h complete before nodecnt)

__device__ __forceinline__ int load_idx(const void* p, long long i, int is32) {
    if (is32) return ((const int*)p)[i];
    return (int)((const long long*)p)[i];
}

// ---- self-detect int32 vs int64 storage of edge_index ----------------------
__device__ int edge_is32(const void* p) {
    __shared__ int sflag;
    if (threadIdx.x == 0) sflag = 0;
    __syncthreads();
    const int* w = (const int*)p;
    int any = 0;
    for (int k = threadIdx.x; k < 2048; k += blockDim.x)
        if (w[2 * k + 1] != 0) any = 1;
    if (any) atomicOr(&sflag, 1);
    __syncthreads();
    return sflag;
}

// batch is sorted from graph 0; sample entries 1024..2047 (nonzero if int32).
__device__ int batch_is32(const void* p) {
    __shared__ int sflag;
    if (threadIdx.x == 0) sflag = 0;
    __syncthreads();
    const int* w = (const int*)p;
    int any = 0;
    for (int k = 1024 + threadIdx.x; k < 2048; k += blockDim.x)
        if (w[2 * k + 1] != 0) any = 1;
    if (any) atomicOr(&sflag, 1);
    __syncthreads();
    return sflag;
}

// ---- matmul tile: h[n] = x[n] @ W_in (UNSCALED), 256 nodes/block -----------
__device__ void mm_span(int nbase, const float* __restrict__ x,
                        const float* __restrict__ W, float* __restrict__ h) {
    int n = nbase + (int)threadIdx.x;
    if (n >= N_NODES) return;
    const float4* xr = (const float4*)(x + (size_t)n * FEAT);
    float acc[EMB];
#pragma unroll
    for (int j = 0; j < EMB; ++j) acc[j] = 0.0f;
#pragma unroll 4
    for (int k4 = 0; k4 < FEAT / 4; ++k4) {
        float4 v = xr[k4];
        const float* w = W + k4 * 4 * EMB;
#pragma unroll
        for (int j = 0; j < EMB; ++j) {
            float a = acc[j];
            a = fmaf(v.x, w[0 * EMB + j], a);
            a = fmaf(v.y, w[1 * EMB + j], a);
            a = fmaf(v.z, w[2 * EMB + j], a);
            a = fmaf(v.w, w[3 * EMB + j], a);
            acc[j] = a;
        }
    }
    float4* o = (float4*)(h + (size_t)n * HP);
    o[0] = make_float4(acc[0], acc[1], acc[2], acc[3]);
    o[1] = make_float4(acc[4], acc[5], acc[6], 0.0f);
}

// ---- pass 1: block-local counting sort by bucket (+ ALL matmul tiles) ------
__global__ void k_sortblk(const void* __restrict__ eidx, int* __restrict__ T,
                          int* __restrict__ gpk, const float* __restrict__ x,
                          const float* __restrict__ W, float* __restrict__ h) {
    if (blockIdx.x >= NB_A) { mm_span(((int)blockIdx.x - NB_A) * 256, x, W, h); return; }
    __shared__ int stage[TILE_A];        // 25 KB
    __shared__ int bins[NBUCK];
    __shared__ int cur[NBUCK];
    __shared__ int wsum[4];
    int is32 = edge_is32(eidx);
    const int b = (int)blockIdx.x, t = (int)threadIdx.x;
    for (int k = t; k < NBUCK; k += 256) bins[k] = 0;
    __syncthreads();
    long long e0 = (long long)b * TILE_A;
    int pk[NIT], bk[NIT];
#pragma unroll
    for (int it = 0; it < NIT; ++it) {
        int i = it * 256 + t;
        if (i < TILE_A) {
            int src = load_idx(eidx, e0 + i, is32);
            int d   = load_idx(eidx, (long long)N_EDGES + e0 + i, is32);
            pk[it] = src | ((d & DMASK) << 17);   // src<2^17, dstlocal 7 bits
            bk[it] = d >> BSH;
            atomicAdd(&bins[bk[it]], 1);
        } else { pk[it] = 0; bk[it] = -1; }
    }
    __syncthreads();
    // exclusive scan of 782 bins (4-per-thread, wave scan + cross-wave)
    int c0 = (4 * t     < NBUCK) ? bins[4 * t]     : 0;
    int c1 = (4 * t + 1 < NBUCK) ? bins[4 * t + 1] : 0;
    int c2 = (4 * t + 2 < NBUCK) ? bins[4 * t + 2] : 0;
    int c3 = (4 * t + 3 < NBUCK) ? bins[4 * t + 3] : 0;
    int sum4 = c0 + c1 + c2 + c3;
    int inc = sum4;
    for (int o = 1; o < 64; o <<= 1) {
        int u = __shfl_up(inc, o);
        if ((t & 63) >= o) inc += u;
    }
    if ((t & 63) == 63) wsum[t >> 6] = inc;
    __syncthreads();
    int add = 0, wv = t >> 6;
    if (wv >= 1) add += wsum[0];
    if (wv >= 2) add += wsum[1];
    if (wv >= 3) add += wsum[2];
    int excl = inc + add - sum4;
    __syncthreads();
    if (4 * t     < NBUCK) { bins[4 * t]     = excl;                cur[4 * t]     = excl; }
    if (4 * t + 1 < NBUCK) { bins[4 * t + 1] = excl + c0;           cur[4 * t + 1] = excl + c0; }
    if (4 * t + 2 < NBUCK) { bins[4 * t + 2] = excl + c0 + c1;      cur[4 * t + 2] = excl + c0 + c1; }
    if (4 * t + 3 < NBUCK) { bins[4 * t + 3] = excl + c0 + c1 + c2; cur[4 * t + 3] = excl + c0 + c1 + c2; }
    __syncthreads();
    for (int k = t; k < NBUCK; k += 256)
        T[b * TCOLS + k] = b * TILE_A + bins[k];
    if (t == 0) T[b * TCOLS + NBUCK] = (b + 1) * TILE_A;
#pragma unroll
    for (int it = 0; it < NIT; ++it) {
        if (bk[it] >= 0) {
            int slot = atomicAdd(&cur[bk[it]], 1);
            stage[slot] = pk[it];
        }
    }
    __syncthreads();
    for (int i = t; i < TILE_A; i += 256)
        gpk[b * TILE_A + i] = stage[i];
}

// ---- run-table loader: rstart[512] abs starts, rst[513] local prefix -------
__device__ int load_runs(const int* __restrict__ T, int k,
                         int* rstart, int* rst, int* wsum) {
    const int t = (int)threadIdx.x;
    int b0 = 2 * t, b1 = 2 * t + 1;
    int s0 = T[b0 * TCOLS + k], e0 = T[b0 * TCOLS + k + 1];
    int s1 = T[b1 * TCOLS + k], e1 = T[b1 * TCOLS + k + 1];
    rstart[b0] = s0; rstart[b1] = s1;
    int c0 = e0 - s0, c1 = e1 - s1;
    int pr = c0 + c1;
    int inc = pr;
    for (int o = 1; o < 64; o <<= 1) {
        int u = __shfl_up(inc, o);
        if ((t & 63) >= o) inc += u;
    }
    if ((t & 63) == 63) wsum[t >> 6] = inc;
    __syncthreads();
    int add = 0, wv = t >> 6;
    if (wv >= 1) add += wsum[0];
    if (wv >= 2) add += wsum[1];
    if (wv >= 3) add += wsum[2];
    int excl = inc + add - pr;
    rst[b0] = excl;
    rst[b1] = excl + c0;
    if (t == 255) rst[512] = excl + pr;   // total
    __syncthreads();
    return rst[512];
}

__device__ __forceinline__ int run_of(const int* rst, int i) {
    int lo = 0, hi = 512;
    while (lo + 1 < hi) { int m = (lo + hi) >> 1; if (rst[m] <= i) lo = m; else hi = m; }
    return lo;
}

// ---- pass 2: per-node count (chunk-walk) + scale h in place; zero gsum -----
__global__ void k_nodecnt(const int* __restrict__ T, const int* __restrict__ gpk,
                          int* __restrict__ cnt, float* __restrict__ gsum,
                          float* __restrict__ h) {
    __shared__ int rstart[512], rst[513], wsum[4];
    __shared__ int bin[128];
    const int k = (int)blockIdx.x, t = (int)threadIdx.x;
    if (k < 32) {                        // zero gsum[1000*8]
        int idx = k * 256 + t;
        if (idx < N_GRAPHS * 8) gsum[idx] = 0.0f;
    }
    if (t < 128) bin[t] = 0;
    int total = load_runs(T, k, rstart, rst, wsum);
    __syncthreads();
    // consecutive-chunk walk: one search per thread, then linear boundary walk
    int chunk = (total + 255) >> 8;
    int i0 = t * chunk;
    int i1 = i0 + chunk; if (i1 > total) i1 = total;
    if (i0 < total) {
        int cur = run_of(rst, i0);
        int nxt = rst[cur + 1];
        int addr = rstart[cur] + (i0 - rst[cur]);
        for (int i = i0; i < i1; ++i) {
            while (i >= nxt) { ++cur; addr = rstart[cur] + (i - rst[cur]); nxt = rst[cur + 1]; }
            int p = gpk[addr++];
            atomicAdd(&bin[(p >> 17) & DMASK], 1);
        }
    }
    __syncthreads();
    int node = (k << BSH) + t;
    if (t < 128 && node < N_NODES) {
        int c = bin[t];
        cnt[node] = c;
        float di = rsqrtf((float)c + 1.0f);
        float4* hp = (float4*)(h + (size_t)node * HP);
        float4 a = hp[0], cc = hp[1];
        hp[0] = make_float4(a.x * di, a.y * di, a.z * di, a.w * di);
        hp[1] = make_float4(cc.x * di, cc.y * di, cc.z * di, 0.0f);
    }
}

// ---- pass 3: regroup (chunk-walk) + gather (pre-scaled h) + partial pool ---
__global__ void k_ggather(const int* __restrict__ T, const int* __restrict__ gpk,
                          const int* __restrict__ cnt, const float* __restrict__ h,
                          const float* __restrict__ b_in, const void* __restrict__ batch,
                          float* __restrict__ gsum) {
    __shared__ int stage[SEGCAP];        // 19 KB
    __shared__ int rstart[512], rst[513], wsum[4];
    __shared__ int bin[128], loff[128], curs[128], pairv[128];
    __shared__ float gsl[GSPAN][8];
    __shared__ int gmin_s;
    const int k = (int)blockIdx.x, t = (int)threadIdx.x;
    int bis32 = batch_is32(batch);
    if (t == 0) gmin_s = load_idx(batch, (long long)(k << BSH), bis32);
    if (t < GSPAN * 8) ((float*)gsl)[t] = 0.0f;
    int total = load_runs(T, k, rstart, rst, wsum);
    int len = (total > SEGCAP) ? SEGCAP : total;   // statistically unreachable
    if (t < 128) {
        int node = (k << BSH) + t;
        bin[t] = (node < N_NODES) ? cnt[node] : 0;
        curs[t] = 0;
    }
    __syncthreads();
    const int gmin = gmin_s;
    // 2-wave inclusive scan of 128 bins -> loff (exclusive)
    if (t < 128) {
        int v = bin[t];
        int inc = v;
        for (int o = 1; o < 64; o <<= 1) {
            int u = __shfl_up(inc, o);
            if ((t & 63) >= o) inc += u;
        }
        pairv[t] = inc;
    }
    __syncthreads();
    if (t < 128) {
        int v = bin[t];
        int add = (t >= 64) ? pairv[63] : 0;
        loff[t] = pairv[t] + add - v;
    }
    __syncthreads();
    // scatter runs -> LDS stage grouped by node (consecutive-chunk walk)
    int chunk = (len + 255) >> 8;
    int i0 = t * chunk;
    int i1 = i0 + chunk; if (i1 > len) i1 = len;
    if (i0 < len) {
        int cur = run_of(rst, i0);
        int nxt = rst[cur + 1];
        int addr = rstart[cur] + (i0 - rst[cur]);
        for (int i = i0; i < i1; ++i) {
            while (i >= nxt) { ++cur; addr = rstart[cur] + (i - rst[cur]); nxt = rst[cur + 1]; }
            int p = gpk[addr++];
            int dl = (p >> 17) & DMASK;
            int r = atomicAdd(&curs[dl], 1);
            stage[loff[dl] + r] = p & 0x1FFFF;
        }
    }
    __syncthreads();
    // gather: 4 lanes/node, 2 rounds of 64 nodes; pool into gsl
    const float4* h4 = (const float4*)h;
    int q = t & 3;
#pragma unroll
    for (int g4 = 0; g4 < 2; ++g4) {
        int nl = (t >> 2) + g4 * 64;
        int node = (k << BSH) + nl;
        if (node < N_NODES) {
            int o = loff[nl], c = bin[nl];
            float acc[EMB];
#pragma unroll
            for (int j = 0; j < EMB; ++j) acc[j] = 0.0f;
            for (int kk = q; kk < c; kk += 4) {
                int s = stage[o + kk];
                float4 a4 = h4[(size_t)s * 2];      // pre-scaled by dinv[s]
                float4 c4 = h4[(size_t)s * 2 + 1];
                acc[0] += a4.x; acc[1] += a4.y; acc[2] += a4.z; acc[3] += a4.w;
                acc[4] += c4.x; acc[5] += c4.y; acc[6] += c4.z;
            }
            if (q == 0) {                 // self loop (h[node] pre-scaled)
                float4 a4 = h4[(size_t)node * 2];
                float4 c4 = h4[(size_t)node * 2 + 1];
                acc[0] += a4.x; acc[1] += a4.y; acc[2] += a4.z; acc[3] += a4.w;
                acc[4] += c4.x; acc[5] += c4.y; acc[6] += c4.z;
            }
#pragma unroll
            for (int j = 0; j < EMB; ++j) {
                acc[j] += __shfl_xor(acc[j], 1);
                acc[j] += __shfl_xor(acc[j], 2);
            }
            float di = rsqrtf((float)c + 1.0f);
            int j0 = 2 * q;
            float v0 = fmaxf(fmaf(di, acc[j0], b_in[j0]), 0.0f);
            float v1 = (j0 + 1 < EMB)
                     ? fmaxf(fmaf(di, acc[j0 + 1], b_in[j0 + 1]), 0.0f) : 0.0f;
            int g = load_idx(batch, node, bis32);
            int gi = g - gmin;
            if (gi < GSPAN) {             // LDS partial (normal path)
                atomicAdd(&gsl[gi][j0], v0);
                atomicAdd(&gsl[gi][j0 + 1], v1);
            } else {                      // unreachable fallback
                atomicAdd(&gsum[(size_t)g * 8 + j0], v0);
                atomicAdd(&gsum[(size_t)g * 8 + j0 + 1], v1);
            }
        }
    }
    __syncthreads();
    if (t < GSPAN * 8) {
        int r = t >> 3, c = t & 7;
        float v = gsl[r][c];
        int g = gmin + r;
        if (v != 0.0f && g < N_GRAPHS) atomicAdd(&gsum[(size_t)g * 8 + c], v);
    }
}

// ---- pass 4: per-graph mean + logits + softmax (1 thread/graph) ------------
__global__ void k_final(const float* __restrict__ gsum, const void* __restrict__ batch,
                        const float* __restrict__ W_out, const float* __restrict__ b_out,
                        float* __restrict__ out) {
    int is32 = batch_is32(batch);
    int g = (int)blockIdx.x * 256 + (int)threadIdx.x;
    if (g >= N_GRAPHS) return;
    int n0, n1;
    {
        int lo = 0, hi = N_NODES;
        while (lo < hi) { int m = (lo + hi) >> 1; if (load_idx(batch, m, is32) < g) lo = m + 1; else hi = m; }
        n0 = lo;
        hi = N_NODES;
        while (lo < hi) { int m = (lo + hi) >> 1; if (load_idx(batch, m, is32) < g + 1) lo = m + 1; else hi = m; }
        n1 = lo;
    }
    float inv = 1.0f / fmaxf((float)(n1 - n0), 1.0f);
    float sums[EMB];
#pragma unroll
    for (int j = 0; j < EMB; ++j) sums[j] = gsum[(size_t)g * 8 + j] * inv;
    float logit[N_CLASSES];
    float mx = -1e30f;
#pragma unroll
    for (int c = 0; c < N_CLASSES; ++c) {
        float l = b_out[c];
#pragma unroll
        for (int j = 0; j < EMB; ++j)
            l = fmaf(sums[j], W_out[j * N_CLASSES + c], l);
        logit[c] = l;
        mx = fmaxf(mx, l);
    }
    float se = 0.0f;
#pragma unroll
    for (int c = 0; c < N_CLASSES; ++c) {
        logit[c] = expf(logit[c] - mx);
        se += logit[c];
    }
    float is = 1.0f / se;
#pragma unroll
    for (int c = 0; c < N_CLASSES; ++c)
        out[(size_t)g * N_CLASSES + c] = logit[c] * is;
}

extern "C" void kernel_launch(void* const* d_in, const int* in_sizes, int n_in,
                              void* d_out, int out_size, void* d_ws, size_t ws_size,
                              hipStream_t stream) {
    const float* x     = (const float*)d_in[0];
    const void*  eidx  = d_in[1];
    const void*  batch = d_in[2];
    const float* W_in  = (const float*)d_in[3];
    const float* b_in  = (const float*)d_in[4];
    // d_in[5], d_in[6] = W_conv1, b_conv1 — dead code in reference.
    const float* W_out = (const float*)d_in[7];
    const float* b_out = (const float*)d_in[8];
    float* out = (float*)d_out;

    // ---- workspace layout (~18.5 MB); h 16B-aligned ------------------------
    int*   gpk  = (int*)d_ws;                    // 3,200,000 ints
    int*   T    = gpk + N_EDGES;                 // 512*783 = 400,896 ints
    int*   cnt  = T + NB_A * TCOLS;              // 100,000 ints
    float* h    = (float*)(cnt + N_NODES);       // 800,000 f (16B-aligned)
    float* gsum = h + (size_t)N_NODES * HP;      // 8,000 f

    const int B = 256;
    k_sortblk<<<NB_A + MMF, B, 0, stream>>>(eidx, T, gpk, x, W_in, h);
    k_nodecnt<<<NBUCK, B, 0, stream>>>(T, gpk, cnt, gsum, h);
    k_ggather<<<NBUCK, B, 0, stream>>>(T, gpk, cnt, h, b_in, batch, gsum);
    k_final  <<<(N_GRAPHS + B - 1) / B, B, 0, stream>>>(gsum, batch, W_out, b_out, out);
}

// Round 20
// 135.631 us; speedup vs baseline: 1.1069x; 1.1069x over previous
//
#include <hip/hip_runtime.h>

#define N_NODES   100000
#define N_EDGES   3200000
#define N_GRAPHS  1000
#define FEAT      512
#define EMB       7
#define HP        8      // padded per-node feature stride
#define N_CLASSES 10

#define BSH       8      // 256 nodes per bucket
#define DMASK     255
#define NBUCK     391    // ceil(100000/256)
#define TCOLS     392    // NBUCK+1 (row-end sentinel)
#define NB_A      512    // sort blocks
#define TILE_A    6250   // 512*6250 == 3.2M exactly
#define NIT       25     // ceil(TILE_A/256)
#define SEGCAP    9216   // bucket total: mean 8192, +11 sigma
#define GSPAN     16     // max graphs per bucket handled in LDS
#define MMF       391    // ALL matmul tiles in k_sortblk (h complete before nodecnt)

__device__ __forceinline__ int load_idx(const void* p, long long i, int is32) {
    if (is32) return ((const int*)p)[i];
    return (int)((const long long*)p)[i];
}

// ---- self-detect int32 vs int64 storage of edge_index ----------------------
__device__ int edge_is32(const void* p) {
    __shared__ int sflag;
    if (threadIdx.x == 0) sflag = 0;
    __syncthreads();
    const int* w = (const int*)p;
    int any = 0;
    for (int k = threadIdx.x; k < 2048; k += blockDim.x)
        if (w[2 * k + 1] != 0) any = 1;
    if (any) atomicOr(&sflag, 1);
    __syncthreads();
    return sflag;
}

// batch is sorted from graph 0; sample entries 1024..2047 (nonzero if int32).
__device__ int batch_is32(const void* p) {
    __shared__ int sflag;
    if (threadIdx.x == 0) sflag = 0;
    __syncthreads();
    const int* w = (const int*)p;
    int any = 0;
    for (int k = 1024 + threadIdx.x; k < 2048; k += blockDim.x)
        if (w[2 * k + 1] != 0) any = 1;
    if (any) atomicOr(&sflag, 1);
    __syncthreads();
    return sflag;
}

// ---- matmul tile: h[n] = x[n] @ W_in (UNSCALED), 256 nodes/block -----------
__device__ void mm_span(int nbase, const float* __restrict__ x,
                        const float* __restrict__ W, float* __restrict__ h) {
    int n = nbase + (int)threadIdx.x;
    if (n >= N_NODES) return;
    const float4* xr = (const float4*)(x + (size_t)n * FEAT);
    float acc[EMB];
#pragma unroll
    for (int j = 0; j < EMB; ++j) acc[j] = 0.0f;
#pragma unroll 4
    for (int k4 = 0; k4 < FEAT / 4; ++k4) {
        float4 v = xr[k4];
        const float* w = W + k4 * 4 * EMB;
#pragma unroll
        for (int j = 0; j < EMB; ++j) {
            float a = acc[j];
            a = fmaf(v.x, w[0 * EMB + j], a);
            a = fmaf(v.y, w[1 * EMB + j], a);
            a = fmaf(v.z, w[2 * EMB + j], a);
            a = fmaf(v.w, w[3 * EMB + j], a);
            acc[j] = a;
        }
    }
    float4* o = (float4*)(h + (size_t)n * HP);
    o[0] = make_float4(acc[0], acc[1], acc[2], acc[3]);
    o[1] = make_float4(acc[4], acc[5], acc[6], 0.0f);
}

// ---- pass 1: block-local counting sort by bucket (+ ALL matmul tiles) ------
__global__ void k_sortblk(const void* __restrict__ eidx, int* __restrict__ T,
                          int* __restrict__ gpk, const float* __restrict__ x,
                          const float* __restrict__ W, float* __restrict__ h) {
    if (blockIdx.x >= NB_A) { mm_span(((int)blockIdx.x - NB_A) * 256, x, W, h); return; }
    __shared__ int stage[TILE_A];        // 25 KB
    __shared__ int bins[NBUCK];
    __shared__ int cur[NBUCK];
    __shared__ int pairv[256];
    __shared__ int wsum[4];
    int is32 = edge_is32(eidx);
    const int b = (int)blockIdx.x, t = (int)threadIdx.x;
    for (int k = t; k < NBUCK; k += 256) bins[k] = 0;
    __syncthreads();
    long long e0 = (long long)b * TILE_A;
    int pk[NIT], bk[NIT];
#pragma unroll
    for (int it = 0; it < NIT; ++it) {
        int i = it * 256 + t;
        if (i < TILE_A) {
            int src = load_idx(eidx, e0 + i, is32);
            int d   = load_idx(eidx, (long long)N_EDGES + e0 + i, is32);
            pk[it] = src | ((d & DMASK) << 17);   // src<2^17, dstlocal 8 bits
            bk[it] = d >> BSH;
            atomicAdd(&bins[bk[it]], 1);
        } else { pk[it] = 0; bk[it] = -1; }
    }
    __syncthreads();
    // exclusive scan of 391 bins (pair-per-thread, wave scan + cross-wave)
    int c0 = (2 * t     < NBUCK) ? bins[2 * t]     : 0;
    int c1 = (2 * t + 1 < NBUCK) ? bins[2 * t + 1] : 0;
    int pr = c0 + c1;
    int inc = pr;
    for (int o = 1; o < 64; o <<= 1) {
        int u = __shfl_up(inc, o);
        if ((t & 63) >= o) inc += u;
    }
    if ((t & 63) == 63) wsum[t >> 6] = inc;
    pairv[t] = inc;
    __syncthreads();
    int add = 0, wv = t >> 6;
    if (wv >= 1) add += wsum[0];
    if (wv >= 2) add += wsum[1];
    if (wv >= 3) add += wsum[2];
    int excl = inc + add - pr;
    __syncthreads();
    if (2 * t     < NBUCK) { bins[2 * t]     = excl;      cur[2 * t]     = excl; }
    if (2 * t + 1 < NBUCK) { bins[2 * t + 1] = excl + c0; cur[2 * t + 1] = excl + c0; }
    __syncthreads();
    for (int k = t; k < NBUCK; k += 256)
        T[b * TCOLS + k] = b * TILE_A + bins[k];
    if (t == 0) T[b * TCOLS + NBUCK] = (b + 1) * TILE_A;
#pragma unroll
    for (int it = 0; it < NIT; ++it) {
        if (bk[it] >= 0) {
            int slot = atomicAdd(&cur[bk[it]], 1);
            stage[slot] = pk[it];
        }
    }
    __syncthreads();
    for (int i = t; i < TILE_A; i += 256)
        gpk[b * TILE_A + i] = stage[i];
}

// ---- run-table loader: rstart[512] abs starts, rst[513] local prefix -------
__device__ int load_runs(const int* __restrict__ T, int k,
                         int* rstart, int* rst, int* wsum) {
    const int t = (int)threadIdx.x;
    int b0 = 2 * t, b1 = 2 * t + 1;
    int s0 = T[b0 * TCOLS + k], e0 = T[b0 * TCOLS + k + 1];
    int s1 = T[b1 * TCOLS + k], e1 = T[b1 * TCOLS + k + 1];
    rstart[b0] = s0; rstart[b1] = s1;
    int c0 = e0 - s0, c1 = e1 - s1;
    int pr = c0 + c1;
    int inc = pr;
    for (int o = 1; o < 64; o <<= 1) {
        int u = __shfl_up(inc, o);
        if ((t & 63) >= o) inc += u;
    }
    if ((t & 63) == 63) wsum[t >> 6] = inc;
    __syncthreads();
    int add = 0, wv = t >> 6;
    if (wv >= 1) add += wsum[0];
    if (wv >= 2) add += wsum[1];
    if (wv >= 3) add += wsum[2];
    int excl = inc + add - pr;
    rst[b0] = excl;
    rst[b1] = excl + c0;
    if (t == 255) rst[512] = excl + pr;   // total
    __syncthreads();
    return rst[512];
}

__device__ __forceinline__ int run_of(const int* rst, int i) {
    int lo = 0, hi = 512;
    while (lo + 1 < hi) { int m = (lo + hi) >> 1; if (rst[m] <= i) lo = m; else hi = m; }
    return lo;
}

// ---- pass 2: per-node count (chunk-walk) + scale h in place; zero gsum -----
__global__ void k_nodecnt(const int* __restrict__ T, const int* __restrict__ gpk,
                          int* __restrict__ cnt, float* __restrict__ gsum,
                          float* __restrict__ h) {
    __shared__ int rstart[512], rst[513], wsum[4];
    __shared__ int bin[256];
    const int k = (int)blockIdx.x, t = (int)threadIdx.x;
    if (k < 32) {                        // zero gsum[1000*8]
        int idx = k * 256 + t;
        if (idx < N_GRAPHS * 8) gsum[idx] = 0.0f;
    }
    bin[t] = 0;
    int total = load_runs(T, k, rstart, rst, wsum);
    __syncthreads();
    // consecutive-chunk walk: one search per thread, then linear boundary walk
    int chunk = (total + 255) >> 8;
    int i0 = t * chunk;
    int i1 = i0 + chunk; if (i1 > total) i1 = total;
    if (i0 < total) {
        int cur = run_of(rst, i0);
        int nxt = rst[cur + 1];
        int addr = rstart[cur] + (i0 - rst[cur]);
        for (int i = i0; i < i1; ++i) {
            while (i >= nxt) { ++cur; addr = rstart[cur] + (i - rst[cur]); nxt = rst[cur + 1]; }
            int p = gpk[addr++];
            atomicAdd(&bin[(p >> 17) & DMASK], 1);
        }
    }
    __syncthreads();
    int node = (k << BSH) + t;
    if (node < N_NODES) {
        int c = bin[t];
        cnt[node] = c;
        float di = rsqrtf((float)c + 1.0f);
        float4* hp = (float4*)(h + (size_t)node * HP);
        float4 a = hp[0], cc = hp[1];
        hp[0] = make_float4(a.x * di, a.y * di, a.z * di, a.w * di);
        hp[1] = make_float4(cc.x * di, cc.y * di, cc.z * di, 0.0f);
    }
}

// ---- pass 3: regroup (chunk-walk) + gather (pre-scaled h) + partial pool ---
__global__ void k_ggather(const int* __restrict__ T, const int* __restrict__ gpk,
                          const int* __restrict__ cnt, const float* __restrict__ h,
                          const float* __restrict__ b_in, const void* __restrict__ batch,
                          float* __restrict__ gsum) {
    __shared__ int stage[SEGCAP];        // 36 KB
    __shared__ int rstart[512], rst[513], wsum[4];
    __shared__ int bin[256], loff[256], curs[256], pairv[256];
    __shared__ float gsl[GSPAN][8];
    __shared__ int gmin_s;
    const int k = (int)blockIdx.x, t = (int)threadIdx.x;
    int bis32 = batch_is32(batch);
    if (t == 0) gmin_s = load_idx(batch, (long long)(k << BSH), bis32);
    if (t < GSPAN * 8) ((float*)gsl)[t] = 0.0f;
    int total = load_runs(T, k, rstart, rst, wsum);
    int len = (total > SEGCAP) ? SEGCAP : total;   // statistically unreachable
    {
        int node = (k << BSH) + t;
        bin[t] = (node < N_NODES) ? cnt[node] : 0;
        curs[t] = 0;
    }
    __syncthreads();
    const int gmin = gmin_s;
    // 4-wave inclusive scan of 256 bins -> loff (exclusive)
    {
        int v = bin[t];
        int inc = v;
        for (int o = 1; o < 64; o <<= 1) {
            int u = __shfl_up(inc, o);
            if ((t & 63) >= o) inc += u;
        }
        pairv[t] = inc;
        __syncthreads();
        int add = 0, wv = t >> 6;
        if (wv >= 1) add += pairv[63];
        if (wv >= 2) add += pairv[127];
        if (wv >= 3) add += pairv[191];
        loff[t] = inc + add - v;
    }
    __syncthreads();
    // scatter runs -> LDS stage grouped by node (consecutive-chunk walk)
    int chunk = (len + 255) >> 8;
    int i0 = t * chunk;
    int i1 = i0 + chunk; if (i1 > len) i1 = len;
    if (i0 < len) {
        int cur = run_of(rst, i0);
        int nxt = rst[cur + 1];
        int addr = rstart[cur] + (i0 - rst[cur]);
        for (int i = i0; i < i1; ++i) {
            while (i >= nxt) { ++cur; addr = rstart[cur] + (i - rst[cur]); nxt = rst[cur + 1]; }
            int p = gpk[addr++];
            int dl = (p >> 17) & DMASK;
            int r = atomicAdd(&curs[dl], 1);
            stage[loff[dl] + r] = p & 0x1FFFF;
        }
    }
    __syncthreads();
    // gather: 4 lanes/node, 4 rounds of 64 nodes; pool into gsl
    const float4* h4 = (const float4*)h;
    int q = t & 3;
#pragma unroll
    for (int g4 = 0; g4 < 4; ++g4) {
        int nl = (t >> 2) + g4 * 64;
        int node = (k << BSH) + nl;
        if (node < N_NODES) {
            int o = loff[nl], c = bin[nl];
            float acc[EMB];
#pragma unroll
            for (int j = 0; j < EMB; ++j) acc[j] = 0.0f;
            for (int kk = q; kk < c; kk += 4) {
                int s = stage[o + kk];
                float4 a4 = h4[(size_t)s * 2];      // pre-scaled by dinv[s]
                float4 c4 = h4[(size_t)s * 2 + 1];
                acc[0] += a4.x; acc[1] += a4.y; acc[2] += a4.z; acc[3] += a4.w;
                acc[4] += c4.x; acc[5] += c4.y; acc[6] += c4.z;
            }
            if (q == 0) {                 // self loop (h[node] pre-scaled)
                float4 a4 = h4[(size_t)node * 2];
                float4 c4 = h4[(size_t)node * 2 + 1];
                acc[0] += a4.x; acc[1] += a4.y; acc[2] += a4.z; acc[3] += a4.w;
                acc[4] += c4.x; acc[5] += c4.y; acc[6] += c4.z;
            }
#pragma unroll
            for (int j = 0; j < EMB; ++j) {
                acc[j] += __shfl_xor(acc[j], 1);
                acc[j] += __shfl_xor(acc[j], 2);
            }
            float di = rsqrtf((float)c + 1.0f);
            int j0 = 2 * q;
            float v0 = fmaxf(fmaf(di, acc[j0], b_in[j0]), 0.0f);
            float v1 = (j0 + 1 < EMB)
                     ? fmaxf(fmaf(di, acc[j0 + 1], b_in[j0 + 1]), 0.0f) : 0.0f;
            int g = load_idx(batch, node, bis32);
            int gi = g - gmin;
            if (gi < GSPAN) {             // LDS partial (normal path)
                atomicAdd(&gsl[gi][j0], v0);
                atomicAdd(&gsl[gi][j0 + 1], v1);
            } else {                      // unreachable fallback
                atomicAdd(&gsum[(size_t)g * 8 + j0], v0);
                atomicAdd(&gsum[(size_t)g * 8 + j0 + 1], v1);
            }
        }
    }
    __syncthreads();
    if (t < GSPAN * 8) {
        int r = t >> 3, c = t & 7;
        float v = gsl[r][c];
        int g = gmin + r;
        if (v != 0.0f && g < N_GRAPHS) atomicAdd(&gsum[(size_t)g * 8 + c], v);
    }
}

// ---- pass 4: per-graph mean + logits + softmax (1 thread/graph) ------------
__global__ void k_final(const float* __restrict__ gsum, const void* __restrict__ batch,
                        const float* __restrict__ W_out, const float* __restrict__ b_out,
                        float* __restrict__ out) {
    int is32 = batch_is32(batch);
    int g = (int)blockIdx.x * 256 + (int)threadIdx.x;
    if (g >= N_GRAPHS) return;
    int n0, n1;
    {
        int lo = 0, hi = N_NODES;
        while (lo < hi) { int m = (lo + hi) >> 1; if (load_idx(batch, m, is32) < g) lo = m + 1; else hi = m; }
        n0 = lo;
        hi = N_NODES;
        while (lo < hi) { int m = (lo + hi) >> 1; if (load_idx(batch, m, is32) < g + 1) lo = m + 1; else hi = m; }
        n1 = lo;
    }
    float inv = 1.0f / fmaxf((float)(n1 - n0), 1.0f);
    float sums[EMB];
#pragma unroll
    for (int j = 0; j < EMB; ++j) sums[j] = gsum[(size_t)g * 8 + j] * inv;
    float logit[N_CLASSES];
    float mx = -1e30f;
#pragma unroll
    for (int c = 0; c < N_CLASSES; ++c) {
        float l = b_out[c];
#pragma unroll
        for (int j = 0; j < EMB; ++j)
            l = fmaf(sums[j], W_out[j * N_CLASSES + c], l);
        logit[c] = l;
        mx = fmaxf(mx, l);
    }
    float se = 0.0f;
#pragma unroll
    for (int c = 0; c < N_CLASSES; ++c) {
        logit[c] = expf(logit[c] - mx);
        se += logit[c];
    }
    float is = 1.0f / se;
#pragma unroll
    for (int c = 0; c < N_CLASSES; ++c)
        out[(size_t)g * N_CLASSES + c] = logit[c] * is;
}

extern "C" void kernel_launch(void* const* d_in, const int* in_sizes, int n_in,
                              void* d_out, int out_size, void* d_ws, size_t ws_size,
                              hipStream_t stream) {
    const float* x     = (const float*)d_in[0];
    const void*  eidx  = d_in[1];
    const void*  batch = d_in[2];
    const float* W_in  = (const float*)d_in[3];
    const float* b_in  = (const float*)d_in[4];
    // d_in[5], d_in[6] = W_conv1, b_conv1 — dead code in reference.
    const float* W_out = (const float*)d_in[7];
    const float* b_out = (const float*)d_in[8];
    float* out = (float*)d_out;

    // ---- workspace layout (~17.3 MB); h 16B-aligned ------------------------
    int*   gpk  = (int*)d_ws;                    // 3,200,000 ints
    int*   T    = gpk + N_EDGES;                 // 512*392 = 200,704 ints
    int*   cnt  = T + NB_A * TCOLS;              // 100,000 ints
    float* h    = (float*)(cnt + N_NODES);       // 800,000 f (byte off 14,002,816)
    float* gsum = h + (size_t)N_NODES * HP;      // 8,000 f

    const int B = 256;
    k_sortblk<<<NB_A + MMF, B, 0, stream>>>(eidx, T, gpk, x, W_in, h);
    k_nodecnt<<<NBUCK, B, 0, stream>>>(T, gpk, cnt, gsum, h);
    k_ggather<<<NBUCK, B, 0, stream>>>(T, gpk, cnt, h, b_in, batch, gsum);
    k_final  <<<(N_GRAPHS + B - 1) / B, B, 0, stream>>>(gsum, batch, W_out, b_out, out);
}